// Round 4
// baseline (272.576 us; speedup 1.0000x reference)
//
#include <hip/hip_runtime.h>
#include <hip/hip_bf16.h>

#define BB 8
#define TT 2048
#define DD 512
#define SQRTD 22.62741699796952f

typedef float fv4 __attribute__((ext_vector_type(4)));
typedef short bv8 __attribute__((ext_vector_type(8)));
typedef short bv4 __attribute__((ext_vector_type(4)));

__device__ __forceinline__ short f2bf(float f) {
  __hip_bfloat16 h = __float2bfloat16(f);
  return *reinterpret_cast<short*>(&h);
}
__device__ __forceinline__ float bf2f(short s) {
  union { unsigned u; float f; } a; a.u = ((unsigned)(unsigned short)s) << 16;
  return a.f;
}

__device__ __forceinline__ void gld_lds16(const void* g, void* l) {
  __builtin_amdgcn_global_load_lds(
      (const __attribute__((address_space(1))) void*)g,
      (__attribute__((address_space(3))) void*)l, 16, 0, 0);
}

// ---------------- K1: fused projection GEMM: C = X @ W^T (f32 in, bf16 out)
__global__ __launch_bounds__(256, 2) void k_proj(
    const float* __restrict__ Xq, const float* __restrict__ Xk, const float* __restrict__ Xv,
    const float* __restrict__ Wq, const float* __restrict__ Wk, const float* __restrict__ Wv,
    short* __restrict__ Qb, short* __restrict__ Kb, short* __restrict__ Vb)
{
  __shared__ short At[128 * 64];
  __shared__ short Bt[128 * 64];
  const int z = blockIdx.z;
  const float* __restrict__ X = (z == 0) ? Xq : (z == 1) ? Xk : Xv;
  const float* __restrict__ W = (z == 0) ? Wq : (z == 1) ? Wk : Wv;
  short* __restrict__ C = (z == 0) ? Qb : (z == 1) ? Kb : Vb;
  const int m0 = blockIdx.x * 128;
  const int n0 = blockIdx.y * 128;
  const int t = threadIdx.x;
  const int lane = t & 63;
  const int w = t >> 6;
  const int wr = (w >> 1) * 64, wc = (w & 1) * 64;
  fv4 acc[4][4] = {};
  for (int kt = 0; kt < DD; kt += 64) {
    #pragma unroll
    for (int j = 0; j < 8; ++j) {
      int f = j * 256 + t;
      int row = f >> 4, c4 = f & 15;
      int byte = (row * 128 + c4 * 8) ^ ((row & 7) << 4);
      fv4 va = *(const fv4*)(X + (size_t)(m0 + row) * DD + kt + c4 * 4);
      bv4 ha;
      #pragma unroll
      for (int e = 0; e < 4; ++e) ha[e] = f2bf(va[e]);
      *(bv4*)((char*)At + byte) = ha;
      fv4 vb = *(const fv4*)(W + (size_t)(n0 + row) * DD + kt + c4 * 4);
      bv4 hb;
      #pragma unroll
      for (int e = 0; e < 4; ++e) hb[e] = f2bf(vb[e]);
      *(bv4*)((char*)Bt + byte) = hb;
    }
    __syncthreads();
    #pragma unroll
    for (int ks = 0; ks < 2; ++ks) {
      bv8 af[4], bfr[4];
      #pragma unroll
      for (int i = 0; i < 4; ++i) {
        int ra = wr + i * 16 + (lane & 15);
        af[i] = *(bv8*)((char*)At + ((ra * 128 + ks * 64 + ((lane >> 4) * 16)) ^ ((ra & 7) << 4)));
        int rb = wc + i * 16 + (lane & 15);
        bfr[i] = *(bv8*)((char*)Bt + ((rb * 128 + ks * 64 + ((lane >> 4) * 16)) ^ ((rb & 7) << 4)));
      }
      #pragma unroll
      for (int mi = 0; mi < 4; ++mi)
        #pragma unroll
        for (int ni = 0; ni < 4; ++ni)
          acc[mi][ni] = __builtin_amdgcn_mfma_f32_16x16x32_bf16(af[mi], bfr[ni], acc[mi][ni], 0, 0, 0);
    }
    __syncthreads();
  }
  #pragma unroll
  for (int mi = 0; mi < 4; ++mi)
    #pragma unroll
    for (int r = 0; r < 4; ++r) {
      int gm = m0 + wr + mi * 16 + ((lane >> 4) << 2) + r;
      #pragma unroll
      for (int ni = 0; ni < 4; ++ni) {
        int gn = n0 + wc + ni * 16 + (lane & 15);
        C[(size_t)gm * DD + gn] = f2bf(acc[mi][ni][r]);
      }
    }
}

// ---------------- K1b: transpose V (B,T,D) -> Vt (B,D,T), bf16
__global__ __launch_bounds__(256) void k_transpose(
    const short* __restrict__ Vb, short* __restrict__ Vt)
{
  __shared__ short tile[64][72];
  const int b = blockIdx.z;
  const int t0 = blockIdx.x * 64;
  const int d0 = blockIdx.y * 64;
  const int t = threadIdx.x;
  #pragma unroll
  for (int j = 0; j < 2; ++j) {
    int f = j * 256 + t;
    int row = f >> 3, c8 = f & 7;
    bv8 v = *(const bv8*)(Vb + ((size_t)b * TT + t0 + row) * DD + d0 + c8 * 8);
    *(bv8*)&tile[row][c8 * 8] = v;
  }
  __syncthreads();
  #pragma unroll
  for (int j = 0; j < 2; ++j) {
    int f = j * 256 + t;
    int drow = f >> 3, c8 = f & 7;
    bv8 v;
    #pragma unroll
    for (int e = 0; e < 8; ++e) v[e] = tile[c8 * 8 + e][drow];
    *(bv8*)(Vt + ((size_t)b * DD + d0 + drow) * TT + t0 + c8 * 8) = v;
  }
}

// ---------------- K2: fused attention.
// QBLK=32 q-rows, 4 waves (rg = q 16-group, kg = key 16-group), KV strips of 32.
// K staged by global_load_lds (pre-swizzled source, linear LDS dest, swizzled reads).
// Counted vmcnt(4) at bar2 keeps mask prefetch in flight; 2 blocks/CU overlap.
__global__ __launch_bounds__(256, 2) void k_attn(
    const short* __restrict__ Qb, const short* __restrict__ Kb,
    const short* __restrict__ Vt, const float* __restrict__ mask,
    float* __restrict__ Out)
{
  __shared__ short Ks[32 * 512];   // 32 rows x 1KB
  __shared__ short Ps[32 * 32];    // 32 rows x 64B, XOR-swizzled
  __shared__ float ls[2][2][16];
  const int b = blockIdx.x;        // batch on x => XCD-pinned
  const int q0 = blockIdx.y * 32;
  const int t = threadIdx.x;
  const int lane = t & 63;
  const int w = t >> 6;            // 0..3
  const int rg = w >> 1, kg = w & 1;
  const int l15 = lane & 15, l4 = lane >> 4;

  const char* __restrict__ Kbase = (const char*)(Kb + (size_t)b * TT * DD);
  const float* __restrict__ Mbase = mask + ((size_t)b * TT + q0) * TT;

  // hoist Q fragments: 16 rows (rg group), full D=512
  bv8 qf[16];
  #pragma unroll
  for (int kk = 0; kk < 16; ++kk)
    qf[kk] = *(const bv8*)(Qb + ((size_t)b * TT + q0 + rg * 16 + l15) * DD + kk * 32 + l4 * 8);

  fv4 o[2][8] = {};
  float rsum[4] = {0.f, 0.f, 0.f, 0.f};
  const int lo16 = lane * 16;

  // prologue: stage K strip 0 (wave w owns rows [8w, 8w+8))
  #pragma unroll
  for (int i = 0; i < 8; ++i) {
    int row = w * 8 + i;
    gld_lds16(Kbase + row * 1024 + (lo16 ^ (i << 4)), Ks + row * 512);
  }
  float mko[4], mkn[4];
  #pragma unroll
  for (int r = 0; r < 4; ++r)
    mko[r] = Mbase[(size_t)(rg * 16 + l4 * 4 + r) * TT + kg * 16 + l15];
  asm volatile("s_waitcnt vmcnt(0) lgkmcnt(0)\n\ts_barrier" ::: "memory");

  for (int nt = 0; nt < TT / 32; ++nt) {
    const int ntn = (nt + 1) & (TT / 32 - 1);

    // V(t): wave w owns d-cols [128w, 128w+128)
    bv8 vreg[8];
    #pragma unroll
    for (int ni = 0; ni < 8; ++ni)
      vreg[ni] = *(const bv8*)(Vt + ((size_t)b * DD + w * 128 + ni * 16 + l15) * TT + nt * 32 + l4 * 8);

    // QK^T: 16x16 tile per wave, 4 independent chains
    const int krow = kg * 16 + l15;
    const int ksw = (krow & 7) << 4;
    fv4 s0 = {}, s1 = {}, s2 = {}, s3 = {};
    __builtin_amdgcn_s_setprio(1);
    #pragma unroll
    for (int kk = 0; kk < 16; kk += 4) {
      bv8 kf0 = *(const bv8*)((const char*)Ks + krow * 1024 + (((kk + 0) * 64 + l4 * 16) ^ ksw));
      bv8 kf1 = *(const bv8*)((const char*)Ks + krow * 1024 + (((kk + 1) * 64 + l4 * 16) ^ ksw));
      bv8 kf2 = *(const bv8*)((const char*)Ks + krow * 1024 + (((kk + 2) * 64 + l4 * 16) ^ ksw));
      bv8 kf3 = *(const bv8*)((const char*)Ks + krow * 1024 + (((kk + 3) * 64 + l4 * 16) ^ ksw));
      s0 = __builtin_amdgcn_mfma_f32_16x16x32_bf16(qf[kk + 0], kf0, s0, 0, 0, 0);
      s1 = __builtin_amdgcn_mfma_f32_16x16x32_bf16(qf[kk + 1], kf1, s1, 0, 0, 0);
      s2 = __builtin_amdgcn_mfma_f32_16x16x32_bf16(qf[kk + 2], kf2, s2, 0, 0, 0);
      s3 = __builtin_amdgcn_mfma_f32_16x16x32_bf16(qf[kk + 3], kf3, s3, 0, 0, 0);
    }
    __builtin_amdgcn_s_setprio(0);
    fv4 sa = (s0 + s1) + (s2 + s3);

    // epilogue: scale + mask + exp -> Ps (swizzled), partial row sums
    #pragma unroll
    for (int r = 0; r < 4; ++r) {
      int row = rg * 16 + l4 * 4 + r;
      float s = sa[r] * SQRTD + mko[r];
      float p = __expf(s);
      short pb = f2bf(p);
      rsum[r] += bf2f(pb);
      *((short*)((char*)Ps + ((row * 64 + (kg * 16 + l15) * 2) ^ ((row & 7) << 4)))) = pb;
    }

    // bar1: Ps visible; all waves done reading Ks(t). No vmcnt drain.
    asm volatile("s_waitcnt lgkmcnt(0)\n\ts_barrier" ::: "memory");

    // stage K(t+1) directly to LDS (async, vmcnt-tracked)
    const char* Kstrip = Kbase + (size_t)ntn * 32 * 1024;
    #pragma unroll
    for (int i = 0; i < 8; ++i) {
      int row = w * 8 + i;
      gld_lds16(Kstrip + row * 1024 + (lo16 ^ (i << 4)), Ks + row * 512);
    }
    // keep glds older than mask loads in the vmcnt FIFO
    __builtin_amdgcn_sched_barrier(0);
    #pragma unroll
    for (int r = 0; r < 4; ++r)
      mkn[r] = Mbase[(size_t)(rg * 16 + l4 * 4 + r) * TT + ntn * 32 + kg * 16 + l15];

    // PV: O[32q x 128d] for this wave's d-cols
    __builtin_amdgcn_s_setprio(1);
    #pragma unroll
    for (int mi = 0; mi < 2; ++mi) {
      int prow = mi * 16 + l15;
      bv8 pa = *(const bv8*)((const char*)Ps + ((prow * 64 + l4 * 16) ^ ((prow & 7) << 4)));
      #pragma unroll
      for (int ni = 0; ni < 8; ++ni)
        o[mi][ni] = __builtin_amdgcn_mfma_f32_16x16x32_bf16(pa, vreg[ni], o[mi][ni], 0, 0, 0);
    }
    __builtin_amdgcn_s_setprio(0);
    #pragma unroll
    for (int r = 0; r < 4; ++r) mko[r] = mkn[r];

    // bar2: own 8 glds complete (vmcnt 8+4 -> 4), masks stay in flight.
    asm volatile("s_waitcnt vmcnt(4) lgkmcnt(0)\n\ts_barrier" ::: "memory");
  }

  // row-sum reduction over 16 key-residues, then across kg
  #pragma unroll
  for (int r = 0; r < 4; ++r) {
    float v = rsum[r];
    v += __shfl_xor(v, 1);
    v += __shfl_xor(v, 2);
    v += __shfl_xor(v, 4);
    v += __shfl_xor(v, 8);
    if (l15 == 0) ls[rg][kg][l4 * 4 + r] = v;
  }
  __syncthreads();
  #pragma unroll
  for (int mi = 0; mi < 2; ++mi)
    #pragma unroll
    for (int r = 0; r < 4; ++r) {
      int idx = l4 * 4 + r;
      float inv = 1.0f / (ls[mi][0][idx] + ls[mi][1][idx]);
      int grow = q0 + mi * 16 + idx;
      #pragma unroll
      for (int ni = 0; ni < 8; ++ni)
        Out[((size_t)b * TT + grow) * DD + w * 128 + ni * 16 + l15] = o[mi][ni][r] * inv;
    }
}

extern "C" void kernel_launch(void* const* d_in, const int* in_sizes, int n_in,
                              void* d_out, int out_size, void* d_ws, size_t ws_size,
                              hipStream_t stream) {
  const float* ft_q = (const float*)d_in[0];
  const float* ft_k = (const float*)d_in[1];
  const float* ft_v = (const float*)d_in[2];
  const float* mask = (const float*)d_in[3];
  const float* Wq   = (const float*)d_in[4];
  const float* Wk   = (const float*)d_in[5];
  const float* Wv   = (const float*)d_in[6];
  float* Out = (float*)d_out;

  const size_t nBTD = (size_t)BB * TT * DD;
  short* Qb = (short*)d_ws;
  short* Kb = Qb + nBTD;
  short* Vb = Kb + nBTD;
  short* Vt = Vb + nBTD;

  k_proj<<<dim3(128, 4, 3), 256, 0, stream>>>(ft_q, ft_k, ft_v, Wq, Wk, Wv, Qb, Kb, Vb);
  k_transpose<<<dim3(TT / 64, DD / 64, BB), 256, 0, stream>>>(Vb, Vt);
  k_attn<<<dim3(BB, TT / 32), 256, 0, stream>>>(Qb, Kb, Vt, mask, Out);
}